// Round 6
// baseline (345.974 us; speedup 1.0000x reference)
//
#include <hip/hip_runtime.h>
#include <cstdint>
#include <cstddef>

typedef __bf16 bf16_t;
typedef __bf16 bf16x8 __attribute__((ext_vector_type(8)));
typedef __bf16 bf16x4 __attribute__((ext_vector_type(4)));
typedef float  f32x4  __attribute__((ext_vector_type(4)));
typedef float  f32x16 __attribute__((ext_vector_type(16)));

#define MFMA16(a, b, c) __builtin_amdgcn_mfma_f32_16x16x32_bf16((a), (b), (c), 0, 0, 0)
#define MFMA32(a, b, c) __builtin_amdgcn_mfma_f32_32x32x16_bf16((a), (b), (c), 0, 0, 0)
#define CVTPK(d, a, b) \
  asm("v_cvt_pk_bf16_f32 %0, %1, %2" : "=v"(d) : "v"(a), "v"(b))
#define PLSWAP(a, b) \
  asm("v_permlane32_swap_b32 %0, %1" : "+v"(a), "+v"(b))

// async global->LDS, 16B per lane. LDS dest must be wave-linear (base + lane*16).
__device__ __forceinline__ void gload_lds16(const bf16_t* g, bf16_t* l) {
  __builtin_amdgcn_global_load_lds(
      (__attribute__((address_space(1))) void*)((void*)g),
      (__attribute__((address_space(3))) void*)l, 16, 0, 0);
}

// ---------------------------------------------------------------------------
// x convert: f32 -> bf16, 4 elems/thread.
// ---------------------------------------------------------------------------
__global__ __launch_bounds__(256) void cvt_f32_bf16(
    const float* __restrict__ in, bf16_t* __restrict__ out, int n) {
  const int i = (blockIdx.x * 256 + threadIdx.x) * 4;
  if (i + 3 < n) {
    const float4 v = *(const float4*)(in + i);
    bf16x4 o;
    o[0] = (bf16_t)v.x; o[1] = (bf16_t)v.y; o[2] = (bf16_t)v.z; o[3] = (bf16_t)v.w;
    *(bf16x4*)(out + i) = o;
  }
}

// ---------------------------------------------------------------------------
// Weight transpose+convert: in f32 [R][C] -> out bf16 [C][R]; R,C mult of 32.
// ---------------------------------------------------------------------------
__global__ __launch_bounds__(256) void transpose_f32_bf16(
    const float* __restrict__ in, bf16_t* __restrict__ out, int R, int C) {
  __shared__ bf16_t tile[32][33];
  const int bc = blockIdx.x * 32, br = blockIdx.y * 32;
  const int tx = threadIdx.x, ty = threadIdx.y;  // (32, 8)
#pragma unroll
  for (int i = 0; i < 32; i += 8)
    tile[ty + i][tx] = (bf16_t)in[(size_t)(br + ty + i) * C + bc + tx];
  __syncthreads();
#pragma unroll
  for (int i = 0; i < 32; i += 8)
    out[(size_t)(bc + ty + i) * R + br + tx] = tile[tx][ty + i];
}

// ---------------------------------------------------------------------------
// GEMM: C[M][N] = A[M][K] @ B[K][N], with Bt given as B^T row-major [N][K].
// 128x128 tile, BK=32, 256 threads = 4 waves (2x2), each wave 64x64 (4x4 frags).
// EPI==0: f32 store to Cout (row stride N) -- final output.
// EPI==1: QKV split epilogue (bf16): Q cols (<2048) pre-scaled by 1/16;
//         cols <4096 -> qk buffer [M][4096]; cols >=4096 (V) -> transposed
//         store vt[(b*8+h)*256+d][2048] at token.
// ---------------------------------------------------------------------------
template <int EPI>
__global__ __launch_bounds__(256) void gemm_bt(
    const bf16_t* __restrict__ A, const bf16_t* __restrict__ Bt,
    void* __restrict__ Cout, bf16_t* __restrict__ Vt, int M, int N, int K) {
  __shared__ __align__(16) bf16_t As[128 * 32];
  __shared__ __align__(16) bf16_t Bs[128 * 32];
  const int tid = threadIdx.x;
  const int lane = tid & 63, w = tid >> 6;
  const int wm = w >> 1, wn = w & 1;
  const int bm = blockIdx.y * 128, bn = blockIdx.x * 128;
  const int l15 = lane & 15, l4 = lane >> 4;

  f32x4 acc[4][4] = {};

  for (int k0 = 0; k0 < K; k0 += 32) {
    __syncthreads();
#pragma unroll
    for (int i = 0; i < 2; ++i) {
      const int idx = i * 256 + tid;
      const int r = idx >> 2, s = idx & 3;
      const int ss = s ^ (r & 3);  // pre-swizzled source seg (XOR involution)
      gload_lds16(A + (size_t)(bm + r) * K + k0 + ss * 8, &As[idx * 8]);
      gload_lds16(Bt + (size_t)(bn + r) * K + k0 + ss * 8, &Bs[idx * 8]);
    }
    __syncthreads();
    bf16x8 af[4], bfr[4];
#pragma unroll
    for (int f = 0; f < 4; ++f) {
      const int ra = wm * 64 + f * 16 + l15;
      const int rb = wn * 64 + f * 16 + l15;
      af[f]  = *(const bf16x8*)&As[ra * 32 + (l4 ^ (ra & 3)) * 8];
      bfr[f] = *(const bf16x8*)&Bs[rb * 32 + (l4 ^ (rb & 3)) * 8];
    }
#pragma unroll
    for (int i = 0; i < 4; ++i)
#pragma unroll
      for (int j = 0; j < 4; ++j) acc[i][j] = MFMA16(af[i], bfr[j], acc[i][j]);
  }

#pragma unroll
  for (int i = 0; i < 4; ++i) {
    const int gr = bm + wm * 64 + i * 16 + l4 * 4;  // 4 consecutive rows gr..gr+3
#pragma unroll
    for (int j = 0; j < 4; ++j) {
      const int gc = bn + wn * 64 + j * 16 + l15;
      if constexpr (EPI == 0) {
        float* C = (float*)Cout;
#pragma unroll
        for (int r = 0; r < 4; ++r)
          C[(size_t)(gr + r) * N + gc] = acc[i][j][r];
      } else {
        bf16_t* C = (bf16_t*)Cout;
        if (gc < 2048) {  // Q region: pre-scale by 1/sqrt(256)
#pragma unroll
          for (int r = 0; r < 4; ++r)
            C[(size_t)(gr + r) * 4096 + gc] = (bf16_t)(acc[i][j][r] * 0.0625f);
        } else if (gc < 4096) {  // K region
#pragma unroll
          for (int r = 0; r < 4; ++r)
            C[(size_t)(gr + r) * 4096 + gc] = (bf16_t)acc[i][j][r];
        } else {  // V region: write transposed vt[(b*8+h)*256+d][2048]
          const int c = gc - 4096, h = c >> 8, d = c & 255;
          const int b = gr >> 11, lt = gr & 2047;
          bf16x4 pk;
#pragma unroll
          for (int r = 0; r < 4; ++r) pk[r] = (bf16_t)acc[i][j][r];
          *(bf16x4*)&Vt[((size_t)(b * 8 + h) * 256 + d) * 2048 + lt] = pk;
        }
      }
    }
  }
}

// ---------------------------------------------------------------------------
// Flash attention, 32x32 MFMA, in-register P (cvt_pk + permlane32_swap),
// double-buffered K/V via global_load_lds with counted vmcnt.
// KVBLK=32 -> LDS 64KB -> 2 blocks/CU (independent blocks overlap MFMA vs
// VALU/staging). Grid: 512 blocks (XCD-swizzled) = 16 q-tiles x 32 bh, all
// co-resident. Block 256 = 4 waves; wave w owns q cols [qt*128+w*32, +32),
// full d=256. Per kv iter (32 keys): S^T = mfma32(K,Q) x 16 ksteps ->
// per-lane softmax -> P-frags in regs -> O^T += mfma32(V^T,P) (8 dt x 2 ks).
// ---------------------------------------------------------------------------
__global__ __launch_bounds__(256, 2) void attn_fwd(
    const bf16_t* __restrict__ qk, const bf16_t* __restrict__ vt,
    bf16_t* __restrict__ ao) {
  __shared__ __align__(16) bf16_t Ks[2][32 * 256];   // 2 x 16KB
  __shared__ __align__(16) bf16_t Vs[2][256 * 32];   // 2 x 16KB
  const int tid = threadIdx.x, lane = tid & 63, w = tid >> 6;
  const int l31 = lane & 31, h5 = lane >> 5;
  const int p4 = l31 & 15, p2 = l31 & 3;
  // XCD swizzle: 512 blocks, chunk 64 per XCD (4 bh per XCD L2)
  const int bid = blockIdx.x;
  const int swz = (bid & 7) * 64 + (bid >> 3);
  const int qt = swz & 15;          // 16 q-tiles of 128 rows
  const int bh = swz >> 4;          // 32 (b,h) pairs
  const int bb = bh >> 3, hh = bh & 7;

  // Q fragments (B-operand): lane holds Q[q = qcol][d = s*16 + h5*8 + j]
  const int qcol = qt * 128 + w * 32 + l31;
  const bf16_t* qbase =
      qk + (size_t)(bb * 2048 + qcol) * 4096 + hh * 256 + h5 * 8;
  bf16x8 qf[16];
#pragma unroll
  for (int s = 0; s < 16; ++s) qf[s] = *(const bf16x8*)(qbase + s * 16);

  const bf16_t* kg = qk + (size_t)(bb * 2048) * 4096 + 2048 + hh * 256;
  const bf16_t* vg = vt + (size_t)bh * 256 * 2048;

  // stage one 32-key tile pair: K [32][256] (4-bit XOR swz), V^T [256][32]
  // (2-bit XOR swz). 8 gload_lds16 per stage (4KB x 256 threads per chunk).
#define STAGE_TILES(bufidx, tile)                                           \
  {                                                                         \
    const int t32 = (tile) * 32;                                            \
    _Pragma("unroll") for (int c = 0; c < 4; ++c) {                         \
      const int idx = c * 256 + tid;                                        \
      const int kr = idx >> 5, kse = idx & 31;                              \
      gload_lds16(kg + (size_t)(t32 + kr) * 4096 + ((kse ^ (kr & 15)) * 8), \
                  &Ks[bufidx][idx * 8]);                                    \
    }                                                                       \
    _Pragma("unroll") for (int c = 0; c < 4; ++c) {                         \
      const int idx = c * 256 + tid;                                        \
      const int vr = idx >> 2, vse = idx & 3;                               \
      gload_lds16(vg + (size_t)vr * 2048 + t32 + ((vse ^ (vr & 3)) * 8),    \
                  &Vs[bufidx][idx * 8]);                                    \
    }                                                                       \
  }

  STAGE_TILES(0, 0);
  STAGE_TILES(1, 1);

  f32x16 o[8] = {};
  float m = -1e30f, lsum = 0.f;

  for (int kv = 0; kv < 64; ++kv) {
    const int cur = kv & 1;
    asm volatile("s_waitcnt vmcnt(8)" ::: "memory");  // tile kv complete
    __builtin_amdgcn_s_barrier();
    __builtin_amdgcn_sched_barrier(0);
    const bf16_t* Kc = Ks[cur];
    const bf16_t* Vc = Vs[cur];

    // ---- S^T = K @ Q^T: 32 keys x 16 ksteps ----
    f32x16 sa = {};
    __builtin_amdgcn_s_setprio(1);
#pragma unroll
    for (int s = 0; s < 16; ++s) {
      bf16x8 kf = *(const bf16x8*)
          ((const char*)Kc + l31 * 512 + (((2 * s + h5) ^ p4) << 4));
      sa = MFMA32(kf, qf[s], sa);
    }
    __builtin_amdgcn_s_setprio(0);

    // ---- online softmax (q = l31; lane pair l, l^32) ----
    float pm = sa[0];
#pragma unroll
    for (int r = 1; r < 16; ++r) pm = fmaxf(pm, sa[r]);
    pm = fmaxf(pm, __shfl_xor(pm, 32));
    if (!__all(pm <= m)) {  // exact skip: al==1 when max unchanged
      const float mn = fmaxf(m, pm);
      const float al = __expf(m - mn);
      m = mn;
      lsum *= al;
#pragma unroll
      for (int dt = 0; dt < 8; ++dt)
#pragma unroll
        for (int r = 0; r < 16; ++r) o[dt][r] *= al;
    }
    float rs = 0.f;
#pragma unroll
    for (int r = 0; r < 16; ++r) { sa[r] = __expf(sa[r] - m); rs += sa[r]; }
    rs += __shfl_xor(rs, 32);
    lsum += rs;

    // ---- P-frags in regs + PV: O^T += V^T @ P ----
    __builtin_amdgcn_s_setprio(1);
#define PV_KSTEP(SA, c0, s2)                                                \
    {                                                                       \
      unsigned w0, w1, w2, w3;                                              \
      CVTPK(w0, SA[4 * (c0) + 0], SA[4 * (c0) + 1]);                        \
      CVTPK(w2, SA[4 * (c0) + 4], SA[4 * (c0) + 5]);                        \
      PLSWAP(w0, w2);                                                       \
      CVTPK(w1, SA[4 * (c0) + 2], SA[4 * (c0) + 3]);                        \
      CVTPK(w3, SA[4 * (c0) + 6], SA[4 * (c0) + 7]);                        \
      PLSWAP(w1, w3);                                                       \
      union { unsigned u[4]; bf16x8 v; } pu;                                \
      pu.u[0] = w0; pu.u[1] = w1; pu.u[2] = w2; pu.u[3] = w3;               \
      _Pragma("unroll") for (int dt = 0; dt < 8; ++dt) {                    \
        bf16x8 vf = *(const bf16x8*)((const char*)Vc +                      \
            (dt * 32 + l31) * 64 + ((((s2) * 2 + h5) ^ p2) << 4));          \
        o[dt] = MFMA32(vf, pu.v, o[dt]);                                    \
      }                                                                     \
    }
    PV_KSTEP(sa, 0, 0);
    PV_KSTEP(sa, 2, 1);
    __builtin_amdgcn_s_setprio(0);

    __builtin_amdgcn_sched_barrier(0);
    __builtin_amdgcn_s_barrier();     // all waves done reading buf[cur]
    __builtin_amdgcn_sched_barrier(0);
    STAGE_TILES(cur, (kv + 2) & 63);  // prefetch (wraps harmlessly at end)
  }

  // ---- epilogue: normalize, store O^T -> ao[token][hh*256 + d] ----
  const float inv = 1.0f / lsum;
  bf16_t* aor = ao + (size_t)(bb * 2048 + qcol) * 2048 + hh * 256 + 4 * h5;
#pragma unroll
  for (int dt = 0; dt < 8; ++dt)
#pragma unroll
    for (int c = 0; c < 4; ++c) {
      bf16x4 ov;
#pragma unroll
      for (int bq = 0; bq < 4; ++bq) ov[bq] = (bf16_t)(o[dt][4 * c + bq] * inv);
      *(bf16x4*)(aor + dt * 32 + 8 * c) = ov;
    }
}

// ---------------------------------------------------------------------------
extern "C" void kernel_launch(void* const* d_in, const int* in_sizes, int n_in,
                              void* d_out, int out_size, void* d_ws,
                              size_t ws_size, hipStream_t stream) {
  (void)in_sizes; (void)n_in; (void)out_size; (void)ws_size;
  const float* x    = (const float*)d_in[0];  // [8192][256] f32
  const float* wqkv = (const float*)d_in[1];  // [256][6144] f32
  const float* wout = (const float*)d_in[2];  // [2048][256] f32
  float* out = (float*)d_out;                 // [8192][256] f32

  char* ws = (char*)d_ws;
  bf16_t* xb  = (bf16_t*)(ws);                            // [8192][256]   4.2MB
  bf16_t* wqt = (bf16_t*)(ws + 4194304);                  // [6144][256]   3.1MB
  bf16_t* wot = (bf16_t*)(ws + 7340032);                  // [256][2048]   1.0MB
  bf16_t* qkb = (bf16_t*)(ws + 8388608);                  // [8192][4096]  67MB
  bf16_t* vtb = (bf16_t*)(ws + 8388608 + 67108864);       // [32][256][2048] 33.6MB
  bf16_t* aob = (bf16_t*)(ws + 8388608 + 67108864 + 33554432);  // [8192][2048] 33.6MB

  cvt_f32_bf16<<<2048, 256, 0, stream>>>(x, xb, 8192 * 256);
  transpose_f32_bf16<<<dim3(192, 8), dim3(32, 8), 0, stream>>>(wqkv, wqt, 256, 6144);
  transpose_f32_bf16<<<dim3(8, 64), dim3(32, 8), 0, stream>>>(wout, wot, 2048, 256);
  // qkv = x @ W_qkv, split epilogue (Q pre-scaled; Q,K row-major; V transposed)
  gemm_bt<1><<<dim3(48, 64), 256, 0, stream>>>(xb, wqt, qkb, vtb, 8192, 6144, 256);
  // attention
  attn_fwd<<<512, 256, 0, stream>>>(qkb, vtb, aob);
  // out = attn_out @ W_out (f32 store)
  gemm_bt<0><<<dim3(2, 64), 256, 0, stream>>>(aob, wot, out, nullptr, 8192, 256, 2048);
}

// Round 7
// 331.339 us; speedup vs baseline: 1.0442x; 1.0442x over previous
//
#include <hip/hip_runtime.h>
#include <cstdint>
#include <cstddef>

typedef __bf16 bf16_t;
typedef __bf16 bf16x8 __attribute__((ext_vector_type(8)));
typedef __bf16 bf16x4 __attribute__((ext_vector_type(4)));
typedef float  f32x4  __attribute__((ext_vector_type(4)));
typedef float  f32x16 __attribute__((ext_vector_type(16)));

#define MFMA16(a, b, c) __builtin_amdgcn_mfma_f32_16x16x32_bf16((a), (b), (c), 0, 0, 0)
#define MFMA32(a, b, c) __builtin_amdgcn_mfma_f32_32x32x16_bf16((a), (b), (c), 0, 0, 0)
#define CVTPK(d, a, b) \
  asm("v_cvt_pk_bf16_f32 %0, %1, %2" : "=v"(d) : "v"(a), "v"(b))
#define PLSWAP(a, b) \
  asm("v_permlane32_swap_b32 %0, %1" : "+v"(a), "+v"(b))

// async global->LDS, 16B per lane. LDS dest must be wave-linear (base + lane*16).
__device__ __forceinline__ void gload_lds16(const bf16_t* g, bf16_t* l) {
  __builtin_amdgcn_global_load_lds(
      (__attribute__((address_space(1))) void*)((void*)g),
      (__attribute__((address_space(3))) void*)l, 16, 0, 0);
}

// ---------------------------------------------------------------------------
// x convert: f32 -> bf16, 4 elems/thread.
// ---------------------------------------------------------------------------
__global__ __launch_bounds__(256) void cvt_f32_bf16(
    const float* __restrict__ in, bf16_t* __restrict__ out, int n) {
  const int i = (blockIdx.x * 256 + threadIdx.x) * 4;
  if (i + 3 < n) {
    const float4 v = *(const float4*)(in + i);
    bf16x4 o;
    o[0] = (bf16_t)v.x; o[1] = (bf16_t)v.y; o[2] = (bf16_t)v.z; o[3] = (bf16_t)v.w;
    *(bf16x4*)(out + i) = o;
  }
}

// ---------------------------------------------------------------------------
// Weight transpose+convert: in f32 [R][C] -> out bf16 [C][R]; R,C mult of 32.
// ---------------------------------------------------------------------------
__global__ __launch_bounds__(256) void transpose_f32_bf16(
    const float* __restrict__ in, bf16_t* __restrict__ out, int R, int C) {
  __shared__ bf16_t tile[32][33];
  const int bc = blockIdx.x * 32, br = blockIdx.y * 32;
  const int tx = threadIdx.x, ty = threadIdx.y;  // (32, 8)
#pragma unroll
  for (int i = 0; i < 32; i += 8)
    tile[ty + i][tx] = (bf16_t)in[(size_t)(br + ty + i) * C + bc + tx];
  __syncthreads();
#pragma unroll
  for (int i = 0; i < 32; i += 8)
    out[(size_t)(bc + ty + i) * R + br + tx] = tile[tx][ty + i];
}

// ---------------------------------------------------------------------------
// GEMM: C[M][N] = A[M][K] @ B[K][N], with Bt given as B^T row-major [N][K].
// 128x128 tile, BK=32, 256 threads = 4 waves (2x2), each wave 64x64 (4x4 frags).
// EPI==0: f32 store to Cout (row stride N) -- final output.
// EPI==1: QKV split epilogue (bf16): Q cols (<2048) pre-scaled by 1/16;
//         cols <4096 -> qk buffer [M][4096]; cols >=4096 (V) -> transposed
//         store vt[(b*8+h)*256+d][2048] at token.
// ---------------------------------------------------------------------------
template <int EPI>
__global__ __launch_bounds__(256) void gemm_bt(
    const bf16_t* __restrict__ A, const bf16_t* __restrict__ Bt,
    void* __restrict__ Cout, bf16_t* __restrict__ Vt, int M, int N, int K) {
  __shared__ __align__(16) bf16_t As[128 * 32];
  __shared__ __align__(16) bf16_t Bs[128 * 32];
  const int tid = threadIdx.x;
  const int lane = tid & 63, w = tid >> 6;
  const int wm = w >> 1, wn = w & 1;
  const int bm = blockIdx.y * 128, bn = blockIdx.x * 128;
  const int l15 = lane & 15, l4 = lane >> 4;

  f32x4 acc[4][4] = {};

  for (int k0 = 0; k0 < K; k0 += 32) {
    __syncthreads();
#pragma unroll
    for (int i = 0; i < 2; ++i) {
      const int idx = i * 256 + tid;
      const int r = idx >> 2, s = idx & 3;
      const int ss = s ^ (r & 3);  // pre-swizzled source seg (XOR involution)
      gload_lds16(A + (size_t)(bm + r) * K + k0 + ss * 8, &As[idx * 8]);
      gload_lds16(Bt + (size_t)(bn + r) * K + k0 + ss * 8, &Bs[idx * 8]);
    }
    __syncthreads();
    bf16x8 af[4], bfr[4];
#pragma unroll
    for (int f = 0; f < 4; ++f) {
      const int ra = wm * 64 + f * 16 + l15;
      const int rb = wn * 64 + f * 16 + l15;
      af[f]  = *(const bf16x8*)&As[ra * 32 + (l4 ^ (ra & 3)) * 8];
      bfr[f] = *(const bf16x8*)&Bs[rb * 32 + (l4 ^ (rb & 3)) * 8];
    }
#pragma unroll
    for (int i = 0; i < 4; ++i)
#pragma unroll
      for (int j = 0; j < 4; ++j) acc[i][j] = MFMA16(af[i], bfr[j], acc[i][j]);
  }

#pragma unroll
  for (int i = 0; i < 4; ++i) {
    const int gr = bm + wm * 64 + i * 16 + l4 * 4;  // 4 consecutive rows gr..gr+3
#pragma unroll
    for (int j = 0; j < 4; ++j) {
      const int gc = bn + wn * 64 + j * 16 + l15;
      if constexpr (EPI == 0) {
        float* C = (float*)Cout;
#pragma unroll
        for (int r = 0; r < 4; ++r)
          C[(size_t)(gr + r) * N + gc] = acc[i][j][r];
      } else {
        bf16_t* C = (bf16_t*)Cout;
        if (gc < 2048) {  // Q region: pre-scale by 1/sqrt(256)
#pragma unroll
          for (int r = 0; r < 4; ++r)
            C[(size_t)(gr + r) * 4096 + gc] = (bf16_t)(acc[i][j][r] * 0.0625f);
        } else if (gc < 4096) {  // K region
#pragma unroll
          for (int r = 0; r < 4; ++r)
            C[(size_t)(gr + r) * 4096 + gc] = (bf16_t)acc[i][j][r];
        } else {  // V region: write transposed vt[(b*8+h)*256+d][2048]
          const int c = gc - 4096, h = c >> 8, d = c & 255;
          const int b = gr >> 11, lt = gr & 2047;
          bf16x4 pk;
#pragma unroll
          for (int r = 0; r < 4; ++r) pk[r] = (bf16_t)acc[i][j][r];
          *(bf16x4*)&Vt[((size_t)(b * 8 + h) * 256 + d) * 2048 + lt] = pk;
        }
      }
    }
  }
}

// ---------------------------------------------------------------------------
// Flash attention, 32x32 MFMA, in-register P (cvt_pk + permlane32_swap),
// double-buffered K/V via global_load_lds with counted vmcnt.
// KVBLK=32 -> LDS 64KB -> 2 blocks/CU. Grid: 512 blocks (XCD-swizzled) =
// 16 q-tiles x 32 bh, all co-resident. Block 256 = 4 waves.
// V LDS swizzle: 16B-unit u(d,s) = 4d + (s ^ ((d>>1)&3)) -- bijective,
// conflict-free reads across 8-lane groups, linear-dest compatible.
// Softmax: defer-max (T13, THR=8) -- rescale only when max grows > 8.
// ---------------------------------------------------------------------------
__global__ __launch_bounds__(256, 2) void attn_fwd(
    const bf16_t* __restrict__ qk, const bf16_t* __restrict__ vt,
    bf16_t* __restrict__ ao) {
  __shared__ __align__(16) bf16_t Ks[2][32 * 256];   // 2 x 16KB
  __shared__ __align__(16) bf16_t Vs[2][256 * 32];   // 2 x 16KB
  const int tid = threadIdx.x, lane = tid & 63, w = tid >> 6;
  const int l31 = lane & 31, h5 = lane >> 5;
  const int p4 = l31 & 15, pv2 = (l31 >> 1) & 3;
  // XCD swizzle: 512 blocks, chunk 64 per XCD (4 bh per XCD L2)
  const int bid = blockIdx.x;
  const int swz = (bid & 7) * 64 + (bid >> 3);
  const int qt = swz & 15;          // 16 q-tiles of 128 rows
  const int bh = swz >> 4;          // 32 (b,h) pairs
  const int bb = bh >> 3, hh = bh & 7;

  // Q fragments (B-operand): lane holds Q[q = qcol][d = s*16 + h5*8 + j]
  const int qcol = qt * 128 + w * 32 + l31;
  const bf16_t* qbase =
      qk + (size_t)(bb * 2048 + qcol) * 4096 + hh * 256 + h5 * 8;
  bf16x8 qf[16];
#pragma unroll
  for (int s = 0; s < 16; ++s) qf[s] = *(const bf16x8*)(qbase + s * 16);

  const bf16_t* kg = qk + (size_t)(bb * 2048) * 4096 + 2048 + hh * 256;
  const bf16_t* vg = vt + (size_t)bh * 256 * 2048;

  // stage one 32-key tile pair: K [32][256] (4-bit XOR swz), V^T [256][32]
  // (u = 4d + (s ^ ((d>>1)&3))). 8 gload_lds16 per stage.
#define STAGE_TILES(bufidx, tile)                                           \
  {                                                                         \
    const int t32 = (tile) * 32;                                            \
    _Pragma("unroll") for (int c = 0; c < 4; ++c) {                         \
      const int idx = c * 256 + tid;                                        \
      const int kr = idx >> 5, kse = idx & 31;                              \
      gload_lds16(kg + (size_t)(t32 + kr) * 4096 + ((kse ^ (kr & 15)) * 8), \
                  &Ks[bufidx][idx * 8]);                                    \
    }                                                                       \
    _Pragma("unroll") for (int c = 0; c < 4; ++c) {                         \
      const int idx = c * 256 + tid;                                        \
      const int vr = idx >> 2, vse = idx & 3;                               \
      gload_lds16(vg + (size_t)vr * 2048 + t32 +                            \
                      ((vse ^ ((vr >> 1) & 3)) * 8),                        \
                  &Vs[bufidx][idx * 8]);                                    \
    }                                                                       \
  }

  STAGE_TILES(0, 0);
  STAGE_TILES(1, 1);

  f32x16 o[8] = {};
  float m = -1e30f, lsum = 0.f;

  for (int kv = 0; kv < 64; ++kv) {
    const int cur = kv & 1;
    asm volatile("s_waitcnt vmcnt(8)" ::: "memory");  // tile kv complete
    __builtin_amdgcn_s_barrier();
    __builtin_amdgcn_sched_barrier(0);
    const bf16_t* Kc = Ks[cur];
    const bf16_t* Vc = Vs[cur];

    // ---- S^T = K @ Q^T: 32 keys x 16 ksteps ----
    f32x16 sa = {};
    __builtin_amdgcn_s_setprio(1);
#pragma unroll
    for (int s = 0; s < 16; ++s) {
      bf16x8 kf = *(const bf16x8*)
          ((const char*)Kc + l31 * 512 + (((2 * s + h5) ^ p4) << 4));
      sa = MFMA32(kf, qf[s], sa);
    }
    __builtin_amdgcn_s_setprio(0);

    // ---- online softmax (q = l31; lane pair l, l^32), defer-max THR=8 ----
    float pm = sa[0];
#pragma unroll
    for (int r = 1; r < 16; ++r) pm = fmaxf(pm, sa[r]);
    pm = fmaxf(pm, __shfl_xor(pm, 32));
    if (!__all(pm <= m + 8.0f)) {  // rescale only when max grows > THR
      const float mn = fmaxf(m, pm);
      const float al = __expf(m - mn);
      m = mn;
      lsum *= al;
#pragma unroll
      for (int dt = 0; dt < 8; ++dt)
#pragma unroll
        for (int r = 0; r < 16; ++r) o[dt][r] *= al;
    }
    float rs = 0.f;
#pragma unroll
    for (int r = 0; r < 16; ++r) { sa[r] = __expf(sa[r] - m); rs += sa[r]; }
    rs += __shfl_xor(rs, 32);
    lsum += rs;

    // ---- P-frags in regs + PV: O^T += V^T @ P ----
    __builtin_amdgcn_s_setprio(1);
#define PV_KSTEP(SA, c0, s2)                                                \
    {                                                                       \
      unsigned w0, w1, w2, w3;                                              \
      CVTPK(w0, SA[4 * (c0) + 0], SA[4 * (c0) + 1]);                        \
      CVTPK(w2, SA[4 * (c0) + 4], SA[4 * (c0) + 5]);                        \
      PLSWAP(w0, w2);                                                       \
      CVTPK(w1, SA[4 * (c0) + 2], SA[4 * (c0) + 3]);                        \
      CVTPK(w3, SA[4 * (c0) + 6], SA[4 * (c0) + 7]);                        \
      PLSWAP(w1, w3);                                                       \
      union { unsigned u[4]; bf16x8 v; } pu;                                \
      pu.u[0] = w0; pu.u[1] = w1; pu.u[2] = w2; pu.u[3] = w3;               \
      _Pragma("unroll") for (int dt = 0; dt < 8; ++dt) {                    \
        bf16x8 vf = *(const bf16x8*)((const char*)Vc +                      \
            (dt * 32 + l31) * 64 + ((((s2) * 2 + h5) ^ pv2) << 4));         \
        o[dt] = MFMA32(vf, pu.v, o[dt]);                                    \
      }                                                                     \
    }
    PV_KSTEP(sa, 0, 0);
    PV_KSTEP(sa, 2, 1);
    __builtin_amdgcn_s_setprio(0);

    __builtin_amdgcn_sched_barrier(0);
    __builtin_amdgcn_s_barrier();     // all waves done reading buf[cur]
    __builtin_amdgcn_sched_barrier(0);
    STAGE_TILES(cur, (kv + 2) & 63);  // prefetch (wraps harmlessly at end)
  }

  // ---- epilogue: normalize, store O^T -> ao[token][hh*256 + d] ----
  const float inv = 1.0f / lsum;
  bf16_t* aor = ao + (size_t)(bb * 2048 + qcol) * 2048 + hh * 256 + 4 * h5;
#pragma unroll
  for (int dt = 0; dt < 8; ++dt)
#pragma unroll
    for (int c = 0; c < 4; ++c) {
      bf16x4 ov;
#pragma unroll
      for (int bq = 0; bq < 4; ++bq) ov[bq] = (bf16_t)(o[dt][4 * c + bq] * inv);
      *(bf16x4*)(aor + dt * 32 + 8 * c) = ov;
    }
}

// ---------------------------------------------------------------------------
extern "C" void kernel_launch(void* const* d_in, const int* in_sizes, int n_in,
                              void* d_out, int out_size, void* d_ws,
                              size_t ws_size, hipStream_t stream) {
  (void)in_sizes; (void)n_in; (void)out_size; (void)ws_size;
  const float* x    = (const float*)d_in[0];  // [8192][256] f32
  const float* wqkv = (const float*)d_in[1];  // [256][6144] f32
  const float* wout = (const float*)d_in[2];  // [2048][256] f32
  float* out = (float*)d_out;                 // [8192][256] f32

  char* ws = (char*)d_ws;
  bf16_t* xb  = (bf16_t*)(ws);                            // [8192][256]   4.2MB
  bf16_t* wqt = (bf16_t*)(ws + 4194304);                  // [6144][256]   3.1MB
  bf16_t* wot = (bf16_t*)(ws + 7340032);                  // [256][2048]   1.0MB
  bf16_t* qkb = (bf16_t*)(ws + 8388608);                  // [8192][4096]  67MB
  bf16_t* vtb = (bf16_t*)(ws + 8388608 + 67108864);       // [32][256][2048] 33.6MB
  bf16_t* aob = (bf16_t*)(ws + 8388608 + 67108864 + 33554432);  // [8192][2048] 33.6MB

  cvt_f32_bf16<<<2048, 256, 0, stream>>>(x, xb, 8192 * 256);
  transpose_f32_bf16<<<dim3(192, 8), dim3(32, 8), 0, stream>>>(wqkv, wqt, 256, 6144);
  transpose_f32_bf16<<<dim3(8, 64), dim3(32, 8), 0, stream>>>(wout, wot, 2048, 256);
  // qkv = x @ W_qkv, split epilogue (Q pre-scaled; Q,K row-major; V transposed)
  gemm_bt<1><<<dim3(48, 64), 256, 0, stream>>>(xb, wqt, qkb, vtb, 8192, 6144, 256);
  // attention
  attn_fwd<<<512, 256, 0, stream>>>(qkb, vtb, aob);
  // out = attn_out @ W_out (f32 store)
  gemm_bt<0><<<dim3(2, 64), 256, 0, stream>>>(aob, wot, out, nullptr, 8192, 256, 2048);
}